// Round 18
// baseline (1361.868 us; speedup 1.0000x reference)
//
#include <hip/hip_runtime.h>
#include <hip/hip_bf16.h>

#define Bn   16
#define LATn 512
#define Cn   512
#define Wn   4096
#define Fn   512

using bf16x8 = __attribute__((ext_vector_type(8))) short;
using f32x4  = __attribute__((ext_vector_type(4))) float;

__device__ __forceinline__ unsigned short f2bf(float x) {
    union { float f; unsigned int u; } v; v.f = x;
    unsigned int r = v.u + 0x7fffu + ((v.u >> 16) & 1u);
    return (unsigned short)(r >> 16);
}

__device__ __forceinline__ void gload_lds16(const void* g, void* l) {
    __builtin_amdgcn_global_load_lds(
        (const __attribute__((address_space(1))) unsigned int*)g,
        (__attribute__((address_space(3))) unsigned int*)l, 16, 0, 0);
}

// L1) affine[b][c] = latent . aw[:,c] + ab[c]; 128 blocks, split-K over l
__global__ void k_affine(const float* __restrict__ latent,
                         const float* __restrict__ aw,
                         const float* __restrict__ ab,
                         float* __restrict__ affine) {
    __shared__ float red[4][64];
    const int t  = threadIdx.x;
    const int cl = t & 63, lq = t >> 6;
    const int c  = blockIdx.x * 64 + cl;
    const int b  = blockIdx.y;
    float s = 0.f;
    #pragma unroll 4
    for (int l = lq * 128; l < lq * 128 + 128; ++l)
        s = fmaf(latent[b * LATn + l], aw[(size_t)l * Cn + c], s);
    red[lq][cl] = s;
    __syncthreads();
    if (t < 64)
        affine[b * Cn + blockIdx.x * 64 + t] =
            red[0][t] + red[1][t] + red[2][t] + red[3][t] + ab[blockIdx.x * 64 + t];
}

// L2) fused roles: demod (128 blk) | kt transpose (384 blk) | halo columns xh (256 blk)
__global__ __launch_bounds__(256)
void k_mid(const float* __restrict__ kw,
           const float* __restrict__ affine,
           const float* __restrict__ content,
           float* __restrict__ demod,
           unsigned short* __restrict__ kt,
           unsigned short* __restrict__ xh) {
    __shared__ __align__(16) char shraw[9216];
    const int t   = threadIdx.x;
    const int bid = blockIdx.x;

    if (bid < 128) {
        float (*red)[64] = (float(*)[64])shraw;
        const int fl = t & 63, cq = t >> 6;
        const int f  = (bid & 7) * 64 + fl;
        const int b  = bid >> 3;
        float s = 0.f;
        for (int c = cq * 128; c < cq * 128 + 128; ++c) {
            const float a  = affine[b * Cn + c];
            const float k0 = kw[((size_t)(0 * Cn + c)) * Fn + f];
            const float k1 = kw[((size_t)(1 * Cn + c)) * Fn + f];
            const float k2 = kw[((size_t)(2 * Cn + c)) * Fn + f];
            s = fmaf(k0 * k0 + k1 * k1 + k2 * k2, a * a, s);
        }
        red[cq][fl] = s;
        __syncthreads();
        if (t < 64)
            demod[b * Fn + (bid & 7) * 64 + t] =
                rsqrtf(red[0][t] + red[1][t] + red[2][t] + red[3][t] + 1e-8f);
    } else if (bid < 512) {
        float (*lds)[65] = (float(*)[65])shraw;
        const int e  = bid - 128;
        const int k  = e / 128;
        const int e2 = e % 128;
        const int c0 = (e2 & 15) * 32;
        const int f0 = (e2 >> 4) * 64;
        #pragma unroll
        for (int i = 0; i < 8; ++i) {
            int q = t + 256 * i; int c = q >> 6; int f = q & 63;
            lds[c][f] = kw[((size_t)(k * Cn + c0 + c)) * Fn + f0 + f];
        }
        __syncthreads();
        #pragma unroll
        for (int i = 0; i < 8; ++i) {
            int q = t + 256 * i; int f = q >> 5; int c = q & 31;
            kt[((size_t)(k * Fn + f0 + f)) * Cn + c0 + c] = f2bf(lds[c][f]);
        }
    } else {
        const int e  = bid - 512;
        const int b  = e >> 4;
        const int wb = e & 15;
        #pragma unroll
        for (int i = 0; i < 4; ++i) {
            const int idx = t + 256 * i;
            const int h   = idx >> 9;
            const int c   = idx & 511;
            const int wg  = wb * 256 + (h ? 256 : -1);
            float v = 0.f;
            if ((unsigned)wg < (unsigned)Wn)
                v = content[((size_t)(b * Cn + c)) * Wn + wg] * affine[b * Cn + c];
            xh[(((size_t)(b * 16 + wb)) * 2 + h) * 512 + c] = f2bf(v);
        }
    }
}

// L3) conv-GEMM: 256f x 256w, BK=32, 8 waves, 16x16x32 MFMA, fused modulate.
//    SINGLE-buffered LDS (68 KB) -> 2 blocks/CU: the sibling block's compute
//    overlaps this block's stage phase (cross-block pipe overlap, m114).
//    2 barriers/tile; C-load cover = full compute phase, no backedge live range.
#define BM 256
#define BN 256
#define BK 32
#define KBYTES   (3 * BM * BK * 2)          // 49152
#define XOFF     KBYTES                     // X region at 49152
#define HALO_OFF (KBYTES + BN * BK * 2)     // 65536: [2][512] bf16 = 2048 B
#define ALDS_OFF (HALO_OFF + 2048)          // [512] f32 = 2048 B
#define SMEMB    (ALDS_OFF + 2048)          // 69632 -> 2 blocks/CU

extern __shared__ __align__(16) char smem[];

// 16 coalesced content dwords -> cbuf (c = c0s + cg*16 + j, w = w0 + wq)
#define LOAD_C(c0s) { \
    _Pragma("unroll") for (int j_ = 0; j_ < 16; ++j_) \
        cbuf[j_] = content[((size_t)(b * Cn + (c0s) + cg * 16 + j_)) * Wn + w0 + wq]; }

// modulate + pack + 2x ds_write_b128 into the X region (swizzled, conflict-free)
#define WRITE_X(c0s) { \
    const float* al_ = (const float*)(smem + ALDS_OFF) + (c0s) + cg * 16; \
    unsigned short h_[16]; \
    _Pragma("unroll") for (int j_ = 0; j_ < 16; ++j_) \
        h_[j_] = f2bf(cbuf[j_] * al_[j_]); \
    _Pragma("unroll") for (int i_ = 0; i_ < 2; ++i_) { \
        const int jj_ = cg * 2 + i_; \
        *(uint4*)(smem + XOFF + (size_t)wq * 64 + ((jj_ ^ ((wq >> 1) & 3)) * 16)) \
            = *(const uint4*)(h_ + i_ * 8); } }

// 2 kt chunks (plane P) per thread into the A region
#define ISSUE_PLANE(c0s, P) { \
    _Pragma("unroll") for (int i_ = 0; i_ < 2; ++i_) { \
        const int Q_ = i_ * 512 + t; \
        const int r_ = (Q_ >> 2) & 255; \
        const int j_ = (Q_ & 3) ^ ((r_ >> 1) & 3); \
        gload_lds16(&kt[((size_t)((P) * Fn + f0 + r_)) * Cn + (c0s) + j_ * 8], \
                    smem + (size_t)((P) * 1024 + Q_) * 16); } }

// one tap: frag ds_reads -> lgkm pin -> setprio-wrapped 32 MFMA
#define TAP(K) { \
    bf16x8 af[8]; bf16x8 bv[4]; \
    _Pragma("unroll") for (int m_ = 0; m_ < 8; ++m_) { \
        const int r_ = wm * 128 + m_ * 16 + l15; \
        af[m_] = *(const bf16x8*)(ka + ((K) * 256 + r_) * 32 + (lhi ^ ((r_ >> 1) & 3)) * 8); } \
    _Pragma("unroll") for (int n_ = 0; n_ < 4; ++n_) { \
        const int rl_ = wn * 64 + n_ * 16 + l15 + (K) - 1; \
        const unsigned short* bp_ = xa + rl_ * 32 + (lhi ^ ((rl_ >> 1) & 3)) * 8; \
        if ((K) == 0 && n_ == 0 && rl_ < 0)   bp_ = halo + c0 + lhi * 8; \
        if ((K) == 2 && n_ == 3 && rl_ > 255) bp_ = halo + 512 + c0 + lhi * 8; \
        bv[n_] = *(const bf16x8*)bp_; } \
    asm volatile("s_waitcnt lgkmcnt(0)" ::: "memory"); \
    __builtin_amdgcn_sched_barrier(0); \
    __builtin_amdgcn_s_setprio(1); \
    _Pragma("unroll") for (int n_ = 0; n_ < 4; ++n_) \
        _Pragma("unroll") for (int m_ = 0; m_ < 8; ++m_) \
            acc[m_][n_] = __builtin_amdgcn_mfma_f32_16x16x32_bf16(af[m_], bv[n_], acc[m_][n_], 0, 0, 0); \
    __builtin_amdgcn_s_setprio(0); }

__global__ __launch_bounds__(512, 4)
void k_conv(const unsigned short* __restrict__ kt,
            const float* __restrict__ content,
            const float* __restrict__ affine,
            const unsigned short* __restrict__ xh,
            const float* __restrict__ demod,
            const float* __restrict__ kb,
            float* __restrict__ y) {
    const int t  = threadIdx.x;
    // XCD pair-swizzle (bijective, 512 % 8 == 0)
    const int o  = blockIdx.x;
    const int l  = ((o & 7) << 6) | (o >> 3);
    const int bx = (l >> 1) & 15;   // w tile
    const int f0 = (l & 1) * BM;    // f half
    const int b  = l >> 5;          // batch
    const int w0 = bx * BN;

    const int wave = t >> 6;
    const int lane = t & 63;
    const int wm   = wave >> 2;
    const int wn   = wave & 3;
    const int l15  = lane & 15;
    const int lhi  = lane >> 4;
    const int cg   = t >> 8;      // c 16-group (0/1)
    const int wq   = t & 255;     // w offset in tile

    unsigned short* halo = (unsigned short*)(smem + HALO_OFF); // [2][512] c-natural
    const unsigned short* ka = (const unsigned short*)smem;
    const unsigned short* xa = (const unsigned short*)(smem + XOFF);

    f32x4 acc[8][4];
    #pragma unroll
    for (int m = 0; m < 8; ++m)
        #pragma unroll
        for (int n = 0; n < 4; ++n)
            #pragma unroll
            for (int r = 0; r < 4; ++r)
                acc[m][n][r] = 0.f;

    float cbuf[16];

    // prologue: affine slice -> LDS (visible to all waves), halo, planes(0),
    // C(0); full drain; X(0) write; barrier.
    ((float*)(smem + ALDS_OFF))[t] = affine[b * Cn + t];
    asm volatile("s_waitcnt lgkmcnt(0)" ::: "memory");
    asm volatile("s_barrier" ::: "memory");
    if (t < 128) {
        const int h = t >> 6, c8 = (t & 63) * 8;
        gload_lds16(&xh[(((size_t)(b * 16 + bx)) * 2 + h) * 512 + c8],
                    halo + (size_t)h * 512 + c8);
    }
    ISSUE_PLANE(0, 0);
    ISSUE_PLANE(0, 1);
    ISSUE_PLANE(0, 2);
    LOAD_C(0);
    asm volatile("s_waitcnt vmcnt(0)" ::: "memory");
    WRITE_X(0);
    asm volatile("s_waitcnt lgkmcnt(0)" ::: "memory");
    asm volatile("s_barrier" ::: "memory");

    for (int cc = 0; cc < Cn / BK; ++cc) {
        const int c0 = cc * BK;
        const int c1 = c0 + BK;
        // C(t+1) issued before compute -> full compute phase of latency cover;
        // consumed at this iteration's stage (no backedge-crossing live range).
        if (cc < 15) { LOAD_C(c1); }
        TAP(0)
        TAP(1)
        TAP(2)
        asm volatile("s_barrier" ::: "memory");   // all waves done reading buffer
        if (cc < 15) {
            ISSUE_PLANE(c1, 0);
            ISSUE_PLANE(c1, 1);
            ISSUE_PLANE(c1, 2);
            asm volatile("s_waitcnt vmcnt(6)" ::: "memory");   // drain C(t+1), keep planes
            WRITE_X(c1);
            asm volatile("s_waitcnt vmcnt(0)" ::: "memory");   // drain planes
            asm volatile("s_waitcnt lgkmcnt(0)" ::: "memory"); // X writes done
        }
        asm volatile("s_barrier" ::: "memory");   // buffer ready for next tile
    }

    // epilogue: demod * acc + kb, leaky_relu(0.2)
    #pragma unroll
    for (int m = 0; m < 8; ++m) {
        const int fb = f0 + wm * 128 + m * 16 + lhi * 4;
        const float4 dmv = *(const float4*)&demod[b * Fn + fb];
        const float4 kbv = *(const float4*)&kb[fb];
        const float dmf[4] = {dmv.x, dmv.y, dmv.z, dmv.w};
        const float kbf[4] = {kbv.x, kbv.y, kbv.z, kbv.w};
        #pragma unroll
        for (int n = 0; n < 4; ++n) {
            const int w = w0 + wn * 64 + n * 16 + l15;
            #pragma unroll
            for (int r = 0; r < 4; ++r) {
                float v = fmaf(acc[m][n][r], dmf[r], kbf[r]);
                v = (v >= 0.f) ? v : 0.2f * v;
                y[((size_t)(b * Fn + fb + r)) * Wn + w] = v;
            }
        }
    }
}

extern "C" void kernel_launch(void* const* d_in, const int* in_sizes, int n_in,
                              void* d_out, int out_size, void* d_ws, size_t ws_size,
                              hipStream_t stream) {
    const float* latent  = (const float*)d_in[0];
    const float* content = (const float*)d_in[1];
    const float* aw      = (const float*)d_in[2];
    const float* ab      = (const float*)d_in[3];
    const float* kw      = (const float*)d_in[4];
    const float* kb      = (const float*)d_in[5];
    float* y = (float*)d_out;

    char* ws = (char*)d_ws;
    float*          affine = (float*)(ws);                        // 32 KB
    float*          demod  = (float*)(ws + 32768);                // 32 KB
    unsigned short* kt     = (unsigned short*)(ws + 131072);      // 1.5 MB
    unsigned short* xh     = (unsigned short*)(ws + 2u * 1024u * 1024u); // 512 KB
    if (ws_size < 3u * 1024u * 1024u) return;

    hipFuncSetAttribute((const void*)k_conv,
                        hipFuncAttributeMaxDynamicSharedMemorySize, SMEMB);

    k_affine<<<dim3(Cn / 64, Bn),     256, 0, stream>>>(latent, aw, ab, affine);
    k_mid   <<<dim3(128 + 384 + 256), 256, 0, stream>>>(kw, affine, content, demod, kt, xh);
    k_conv  <<<dim3(512),             512, SMEMB, stream>>>(kt, content, affine, xh, demod, kb, y);
}

// Round 19
// 145.350 us; speedup vs baseline: 9.3696x; 9.3696x over previous
//
#include <hip/hip_runtime.h>
#include <hip/hip_bf16.h>

#define Bn   16
#define LATn 512
#define Cn   512
#define Wn   4096
#define Fn   512

using bf16x8 = __attribute__((ext_vector_type(8))) short;
using f32x4  = __attribute__((ext_vector_type(4))) float;

__device__ __forceinline__ unsigned short f2bf(float x) {
    union { float f; unsigned int u; } v; v.f = x;
    unsigned int r = v.u + 0x7fffu + ((v.u >> 16) & 1u);
    return (unsigned short)(r >> 16);
}

__device__ __forceinline__ void gload_lds16(const void* g, void* l) {
    __builtin_amdgcn_global_load_lds(
        (const __attribute__((address_space(1))) unsigned int*)g,
        (__attribute__((address_space(3))) unsigned int*)l, 16, 0, 0);
}

// L1) affine[b][c] = latent . aw[:,c] + ab[c]; 128 blocks, split-K over l
__global__ void k_affine(const float* __restrict__ latent,
                         const float* __restrict__ aw,
                         const float* __restrict__ ab,
                         float* __restrict__ affine) {
    __shared__ float red[4][64];
    const int t  = threadIdx.x;
    const int cl = t & 63, lq = t >> 6;
    const int c  = blockIdx.x * 64 + cl;
    const int b  = blockIdx.y;
    float s = 0.f;
    #pragma unroll 4
    for (int l = lq * 128; l < lq * 128 + 128; ++l)
        s = fmaf(latent[b * LATn + l], aw[(size_t)l * Cn + c], s);
    red[lq][cl] = s;
    __syncthreads();
    if (t < 64)
        affine[b * Cn + blockIdx.x * 64 + t] =
            red[0][t] + red[1][t] + red[2][t] + red[3][t] + ab[blockIdx.x * 64 + t];
}

// L2) fused roles: demod (128 blk) | kt transpose (384 blk) | halo columns xh (256 blk)
__global__ __launch_bounds__(256)
void k_mid(const float* __restrict__ kw,
           const float* __restrict__ affine,
           const float* __restrict__ content,
           float* __restrict__ demod,
           unsigned short* __restrict__ kt,
           unsigned short* __restrict__ xh) {
    __shared__ __align__(16) char shraw[9216];
    const int t   = threadIdx.x;
    const int bid = blockIdx.x;

    if (bid < 128) {
        float (*red)[64] = (float(*)[64])shraw;
        const int fl = t & 63, cq = t >> 6;
        const int f  = (bid & 7) * 64 + fl;
        const int b  = bid >> 3;
        float s = 0.f;
        for (int c = cq * 128; c < cq * 128 + 128; ++c) {
            const float a  = affine[b * Cn + c];
            const float k0 = kw[((size_t)(0 * Cn + c)) * Fn + f];
            const float k1 = kw[((size_t)(1 * Cn + c)) * Fn + f];
            const float k2 = kw[((size_t)(2 * Cn + c)) * Fn + f];
            s = fmaf(k0 * k0 + k1 * k1 + k2 * k2, a * a, s);
        }
        red[cq][fl] = s;
        __syncthreads();
        if (t < 64)
            demod[b * Fn + (bid & 7) * 64 + t] =
                rsqrtf(red[0][t] + red[1][t] + red[2][t] + red[3][t] + 1e-8f);
    } else if (bid < 512) {
        float (*lds)[65] = (float(*)[65])shraw;
        const int e  = bid - 128;
        const int k  = e / 128;
        const int e2 = e % 128;
        const int c0 = (e2 & 15) * 32;
        const int f0 = (e2 >> 4) * 64;
        #pragma unroll
        for (int i = 0; i < 8; ++i) {
            int q = t + 256 * i; int c = q >> 6; int f = q & 63;
            lds[c][f] = kw[((size_t)(k * Cn + c0 + c)) * Fn + f0 + f];
        }
        __syncthreads();
        #pragma unroll
        for (int i = 0; i < 8; ++i) {
            int q = t + 256 * i; int f = q >> 5; int c = q & 31;
            kt[((size_t)(k * Fn + f0 + f)) * Cn + c0 + c] = f2bf(lds[c][f]);
        }
    } else {
        const int e  = bid - 512;
        const int b  = e >> 4;
        const int wb = e & 15;
        #pragma unroll
        for (int i = 0; i < 4; ++i) {
            const int idx = t + 256 * i;
            const int h   = idx >> 9;
            const int c   = idx & 511;
            const int wg  = wb * 256 + (h ? 256 : -1);
            float v = 0.f;
            if ((unsigned)wg < (unsigned)Wn)
                v = content[((size_t)(b * Cn + c)) * Wn + wg] * affine[b * Cn + c];
            xh[(((size_t)(b * 16 + wb)) * 2 + h) * 512 + c] = f2bf(v);
        }
    }
}

// L3) conv-GEMM (best measured config, R16: conv=124.6us, total=145.9us):
//    256f x 256w, BK=32, 8 waves, 16x16x32 MFMA, 3-phase counted vmcnt,
//    fused in-kernel modulate (coalesced f32 content -> bf16 X in LDS),
//    XCD pair-swizzle. VGPR 124, no spill.
#define BM 256
#define BN 256
#define BK 32
#define KBYTES   (3 * BM * BK * 2)          // 49152 per buffer
#define BUFB     (KBYTES + BN * BK * 2)     // 65536 per buffer
#define HALO_OFF (2 * BUFB)                 // [2][512] bf16 = 2048 B
#define ALDS_OFF (HALO_OFF + 2048)          // [512] f32   = 2048 B
#define SMEMB    (ALDS_OFF + 2048)          // 135168 total

extern __shared__ __align__(16) char smem[];

// 16 coalesced content dwords -> cbuf (c = c0s + cg*16 + j, w = w0 + wq)
#define LOAD_C(c0s) { \
    _Pragma("unroll") for (int j_ = 0; j_ < 16; ++j_) \
        cbuf[j_] = content[((size_t)(b * Cn + (c0s) + cg * 16 + j_)) * Wn + w0 + wq]; }

// modulate + pack + 2x ds_write_b128 into dst X region (swizzled, conflict-free)
#define WRITE_X(dst, c0s) { \
    const float* al_ = (const float*)(smem + ALDS_OFF) + (c0s) + cg * 16; \
    unsigned short h_[16]; \
    _Pragma("unroll") for (int j_ = 0; j_ < 16; ++j_) \
        h_[j_] = f2bf(cbuf[j_] * al_[j_]); \
    _Pragma("unroll") for (int i_ = 0; i_ < 2; ++i_) { \
        const int jj_ = cg * 2 + i_; \
        *(uint4*)((dst) + KBYTES + (size_t)wq * 64 + ((jj_ ^ ((wq >> 1) & 3)) * 16)) \
            = *(const uint4*)(h_ + i_ * 8); } }

// 2 kt chunks (plane P) per thread
#define ISSUE_PLANE(dst, c0s, P) { \
    _Pragma("unroll") for (int i_ = 0; i_ < 2; ++i_) { \
        const int Q_ = i_ * 512 + t; \
        const int r_ = (Q_ >> 2) & 255; \
        const int j_ = (Q_ & 3) ^ ((r_ >> 1) & 3); \
        gload_lds16(&kt[((size_t)((P) * Fn + f0 + r_)) * Cn + (c0s) + j_ * 8], \
                    (dst) + (size_t)((P) * 1024 + Q_) * 16); } }

// one phase = k-tap K: vmcnt(VM) -> barrier -> frag reads -> PRE ->
// lgkmcnt(0)+sched_barrier -> setprio-wrapped 32 MFMA
#define PHASE(K, VM, ...) { \
    asm volatile("s_waitcnt vmcnt(" #VM ")" ::: "memory"); \
    asm volatile("s_barrier" ::: "memory"); \
    bf16x8 af[8]; bf16x8 bv[4]; \
    _Pragma("unroll") for (int m_ = 0; m_ < 8; ++m_) { \
        const int r_ = wm * 128 + m_ * 16 + l15; \
        af[m_] = *(const bf16x8*)(ka + ((K) * 256 + r_) * 32 + (lhi ^ ((r_ >> 1) & 3)) * 8); } \
    _Pragma("unroll") for (int n_ = 0; n_ < 4; ++n_) { \
        const int rl_ = wn * 64 + n_ * 16 + l15 + (K) - 1; \
        const unsigned short* bp_ = xa + rl_ * 32 + (lhi ^ ((rl_ >> 1) & 3)) * 8; \
        if ((K) == 0 && n_ == 0 && rl_ < 0)   bp_ = halo + c0 + lhi * 8; \
        if ((K) == 2 && n_ == 3 && rl_ > 255) bp_ = halo + 512 + c0 + lhi * 8; \
        bv[n_] = *(const bf16x8*)bp_; } \
    __VA_ARGS__; \
    asm volatile("s_waitcnt lgkmcnt(0)" ::: "memory"); \
    __builtin_amdgcn_sched_barrier(0); \
    __builtin_amdgcn_s_setprio(1); \
    _Pragma("unroll") for (int n_ = 0; n_ < 4; ++n_) \
        _Pragma("unroll") for (int m_ = 0; m_ < 8; ++m_) \
            acc[m_][n_] = __builtin_amdgcn_mfma_f32_16x16x32_bf16(af[m_], bv[n_], acc[m_][n_], 0, 0, 0); \
    __builtin_amdgcn_s_setprio(0); }

__global__ __launch_bounds__(512, 1)
void k_conv(const unsigned short* __restrict__ kt,
            const float* __restrict__ content,
            const float* __restrict__ affine,
            const unsigned short* __restrict__ xh,
            const float* __restrict__ demod,
            const float* __restrict__ kb,
            float* __restrict__ y) {
    const int t  = threadIdx.x;
    // XCD pair-swizzle: bijective for 512 blocks (512 % 8 == 0)
    const int o  = blockIdx.x;
    const int l  = ((o & 7) << 6) | (o >> 3);
    const int bx = (l >> 1) & 15;   // w tile
    const int f0 = (l & 1) * BM;    // f half
    const int b  = l >> 5;          // batch
    const int w0 = bx * BN;

    const int wave = t >> 6;
    const int lane = t & 63;
    const int wm   = wave >> 2;
    const int wn   = wave & 3;
    const int l15  = lane & 15;
    const int lhi  = lane >> 4;
    const int cg   = t >> 8;      // c 16-group (0/1)
    const int wq   = t & 255;     // w offset in tile

    unsigned short* halo = (unsigned short*)(smem + HALO_OFF); // [2][512] c-natural

    f32x4 acc[8][4];
    #pragma unroll
    for (int m = 0; m < 8; ++m)
        #pragma unroll
        for (int n = 0; n < 4; ++n)
            #pragma unroll
            for (int r = 0; r < 4; ++r)
                acc[m][n][r] = 0.f;

    float cbuf[16];

    // prologue: affine slice -> LDS, barrier (visibility), halo from xh,
    // C(0) to regs, planes(0) issued, vmcnt(6) keeps planes in flight,
    // X(0) written to buf0.
    {
        float av = affine[b * Cn + t];
        ((float*)(smem + ALDS_OFF))[t] = av;
    }
    asm volatile("s_waitcnt lgkmcnt(0)" ::: "memory");
    asm volatile("s_barrier" ::: "memory");
    if (t < 128) {
        const int h = t >> 6, c8 = (t & 63) * 8;
        gload_lds16(&xh[(((size_t)(b * 16 + bx)) * 2 + h) * 512 + c8],
                    halo + (size_t)h * 512 + c8);
    }
    LOAD_C(0);
    ISSUE_PLANE(smem, 0, 0);
    ISSUE_PLANE(smem, 0, 1);
    ISSUE_PLANE(smem, 0, 2);
    asm volatile("s_waitcnt vmcnt(6)" ::: "memory");   // drain halo + C(0); keep P(0)x6
    WRITE_X(smem, 0);
    asm volatile("s_waitcnt lgkmcnt(0)" ::: "memory");

    int cur = 0;
    // per-wave vmem issue/tile: C=16 (p0), P0+P1=4 (p1), P2=2 (p2).
    // waits: p0 needs P0(t)   -> outstanding {P0,P1,P2}=6, keep 4
    //        p1 needs P1(t)   -> outstanding {P1,P2,C}=20, keep 18
    //        p2 needs P2(t)+C -> outstanding {P2,C,P0',P1'}=22, keep 4
    for (int cc = 0; cc < Cn / BK - 1; ++cc) {
        const unsigned short* ka = (const unsigned short*)(smem + cur * BUFB);
        const unsigned short* xa = ka + 3 * BM * BK;
        char* nbuf = smem + (cur ^ 1) * BUFB;
        const int c0 = cc * BK;
        const int c1 = c0 + BK;
        PHASE(0, 4,  LOAD_C(c1);)
        PHASE(1, 18, ISSUE_PLANE(nbuf, c1, 0); ISSUE_PLANE(nbuf, c1, 1);)
        PHASE(2, 4,  ISSUE_PLANE(nbuf, c1, 2); WRITE_X(nbuf, c1);)
        cur ^= 1;
    }
    {   // peeled last tile: no prefetch; tight waits
        const unsigned short* ka = (const unsigned short*)(smem + cur * BUFB);
        const unsigned short* xa = ka + 3 * BM * BK;
        const int c0 = Cn - BK;
        PHASE(0, 4, )
        PHASE(1, 2, )
        PHASE(2, 0, )
    }

    // epilogue: demod * acc + kb, leaky_relu(0.2)
    #pragma unroll
    for (int m = 0; m < 8; ++m) {
        const int fb = f0 + wm * 128 + m * 16 + lhi * 4;
        const float4 dmv = *(const float4*)&demod[b * Fn + fb];
        const float4 kbv = *(const float4*)&kb[fb];
        const float dmf[4] = {dmv.x, dmv.y, dmv.z, dmv.w};
        const float kbf[4] = {kbv.x, kbv.y, kbv.z, kbv.w};
        #pragma unroll
        for (int n = 0; n < 4; ++n) {
            const int w = w0 + wn * 64 + n * 16 + l15;
            #pragma unroll
            for (int r = 0; r < 4; ++r) {
                float v = fmaf(acc[m][n][r], dmf[r], kbf[r]);
                v = (v >= 0.f) ? v : 0.2f * v;
                y[((size_t)(b * Fn + fb + r)) * Wn + w] = v;
            }
        }
    }
}

extern "C" void kernel_launch(void* const* d_in, const int* in_sizes, int n_in,
                              void* d_out, int out_size, void* d_ws, size_t ws_size,
                              hipStream_t stream) {
    const float* latent  = (const float*)d_in[0];
    const float* content = (const float*)d_in[1];
    const float* aw      = (const float*)d_in[2];
    const float* ab      = (const float*)d_in[3];
    const float* kw      = (const float*)d_in[4];
    const float* kb      = (const float*)d_in[5];
    float* y = (float*)d_out;

    char* ws = (char*)d_ws;
    float*          affine = (float*)(ws);                        // 32 KB
    float*          demod  = (float*)(ws + 32768);                // 32 KB
    unsigned short* kt     = (unsigned short*)(ws + 131072);      // 1.5 MB
    unsigned short* xh     = (unsigned short*)(ws + 2u * 1024u * 1024u); // 512 KB
    if (ws_size < 3u * 1024u * 1024u) return;

    hipFuncSetAttribute((const void*)k_conv,
                        hipFuncAttributeMaxDynamicSharedMemorySize, SMEMB);

    k_affine<<<dim3(Cn / 64, Bn),     256, 0, stream>>>(latent, aw, ab, affine);
    k_mid   <<<dim3(128 + 384 + 256), 256, 0, stream>>>(kw, affine, content, demod, kt, xh);
    k_conv  <<<dim3(512),             512, SMEMB, stream>>>(kt, content, affine, xh, demod, kb, y);
}